// Round 13
// baseline (1414.502 us; speedup 1.0000x reference)
//
#include <hip/hip_runtime.h>
#include <stdint.h>

// Dense MFMA chain: out = leaky(A @ (B @ (B^T @ (A^T @ E)))).
// Intermediates transposed X[256][8192] bf16; 4 GEMMs M=256,N=8192,K=8192.
//   G1 (NN, W=A), G2 (NN, W=B), G3 (NT, W=B), G4 (NT, W=A) + leaky+transpose.
// R13 fixes vs R12: XOR/rotation LDS swizzles (kill 8-16 way conflicts),
// register-prefetch double buffer (overlap W stream with MFMA), K-split 4
// (512 blocks, 2/CU via __launch_bounds__(256,2)).

#define KC 64
#define MROWS 256
#define NBIG 8192
#define KS 4                     // K splits
#define PHALF (MROWS * NBIG)     // one partial = 2,097,152 floats

typedef short  short8  __attribute__((ext_vector_type(8)));
typedef float  float4v __attribute__((ext_vector_type(4)));

__device__ __forceinline__ uint32_t f2bf(float f) {  // RNE fp32 -> bf16
    uint32_t b = __float_as_uint(f);
    return (b + 0x7fffu + ((b >> 16) & 1u)) >> 16;
}

// E [8192][256] fp32 -> XT0 [256][8192] bf16 (transpose via LDS 32x32 tiles)
__global__ __launch_bounds__(256) void cvtE_kernel(const float* __restrict__ E,
                                                   unsigned short* __restrict__ XT) {
    __shared__ float T[32][33];
    const int n0 = blockIdx.x * 32;
    const int d0 = blockIdx.y * 32;
    const int t = threadIdx.x;
    const int a = t >> 5, b = t & 31;
    #pragma unroll
    for (int i = 0; i < 4; ++i) {
        int n = i * 8 + a;
        T[b][n] = E[(size_t)(n0 + n) * 256 + d0 + b];
    }
    __syncthreads();
    #pragma unroll
    for (int i = 0; i < 4; ++i) {
        int d = i * 8 + a;
        XT[(size_t)(d0 + d) * NBIG + n0 + b] = (unsigned short)f2bf(T[d][b]);
    }
}

// One GEMM K-slab: C[256 x 64-slab] partial over K/4.
// Xlds: [m][kq] quads XOR-swizzled (quad ^ (m&7)) -> all b128 ops 2-way max.
// W NT: Wlds[n][kq] same XOR swizzle (b128 fragment reads).
// W NN: Wlds[k][n] UNtransposed, rotation-2 swizzle phys_n=(n+2k)&63;
//       B-fragment built from 8x ds_read_u16 (exactly 2 lanes/bank).
template<int NT>
__global__ __launch_bounds__(256, 2) void gemm_kernel(
        const unsigned short* __restrict__ X,  // [256][8192] bf16
        const float* __restrict__ W,           // [8192][8192] fp32
        float* __restrict__ P) {               // [KS][256][8192] fp32 partials
    __shared__ __align__(16) unsigned short Xlds[MROWS * 64];  // 32 KB
    __shared__ __align__(16) unsigned short Wlds[64 * 64];     // 8 KB
    const int tid  = threadIdx.x;
    const int n0   = blockIdx.x * 64;
    const int ks   = blockIdx.y;
    const int lane = tid & 63;
    const int w    = tid >> 6;
    const int m16  = lane & 15;
    const int q    = lane >> 4;

    float4v acc[16];
    #pragma unroll
    for (int i = 0; i < 16; ++i) acc[i] = (float4v){0.f, 0.f, 0.f, 0.f};

    const int kbeg = ks * (NBIG / KS);
    const int kend = kbeg + NBIG / KS;

    uint4 rx[8];
    float4 rw[4];

    auto loadX = [&](int kb) {
        const uint4* Xg = (const uint4*)X;          // 8 bf16 per uint4
        #pragma unroll
        for (int i = 0; i < 8; ++i) {
            int c = tid + i * 256;
            int m = c >> 3, kq = c & 7;
            rx[i] = Xg[(size_t)m * 1024 + (kb >> 3) + kq];
        }
    };
    auto loadW = [&](int kb) {
        const float4* Wg = (const float4*)W;
        #pragma unroll
        for (int i = 0; i < 4; ++i) {
            int c = tid + i * 256;
            if (NT) {                                // W'[n][k]: stream along k
                int n = c >> 4, kq4 = c & 15;
                rw[i] = Wg[(size_t)(n0 + n) * 2048 + (kb >> 2) + kq4];
            } else {                                 // W[k][n]: stream along n
                int k = c >> 4, nq = c & 15;
                rw[i] = Wg[(size_t)(kb + k) * 2048 + (n0 >> 2) + nq];
            }
        }
    };
    auto storeX = [&]() {
        #pragma unroll
        for (int i = 0; i < 8; ++i) {
            int c = tid + i * 256;
            int m = c >> 3, kq = c & 7;
            *(uint4*)&Xlds[m * 64 + ((kq ^ (m & 7)) << 3)] = rx[i];
        }
    };
    auto storeW = [&]() {
        #pragma unroll
        for (int i = 0; i < 4; ++i) {
            int c = tid + i * 256;
            if (NT) {
                int n = c >> 4, kq4 = c & 15;
                int quad = kq4 >> 1, hf = kq4 & 1;
                uint2 pk;
                pk.x = f2bf(rw[i].x) | (f2bf(rw[i].y) << 16);
                pk.y = f2bf(rw[i].z) | (f2bf(rw[i].w) << 16);
                *(uint2*)&Wlds[n * 64 + ((quad ^ (n & 7)) << 3) + hf * 4] = pk;
            } else {
                int k = c >> 4, nq = c & 15;
                unsigned short v0 = (unsigned short)f2bf(rw[i].x);
                unsigned short v1 = (unsigned short)f2bf(rw[i].y);
                unsigned short v2 = (unsigned short)f2bf(rw[i].z);
                unsigned short v3 = (unsigned short)f2bf(rw[i].w);
                int nb = nq * 4, rot = 2 * k;
                Wlds[k * 64 + ((nb + 0 + rot) & 63)] = v0;
                Wlds[k * 64 + ((nb + 1 + rot) & 63)] = v1;
                Wlds[k * 64 + ((nb + 2 + rot) & 63)] = v2;
                Wlds[k * 64 + ((nb + 3 + rot) & 63)] = v3;
            }
        }
    };

    loadX(kbeg); loadW(kbeg);
    for (int kb = kbeg; kb < kend; kb += KC) {
        storeX(); storeW();
        __syncthreads();
        if (kb + KC < kend) { loadX(kb + KC); loadW(kb + KC); }  // overlap compute
        const int n = w * 16 + m16;
        #pragma unroll
        for (int s = 0; s < 2; ++s) {
            short8 bf;
            if (NT) {
                bf = *(const short8*)&Wlds[n * 64 + ((((s << 2) + q) ^ (n & 7)) << 3)];
            } else {
                #pragma unroll
                for (int j = 0; j < 8; ++j) {
                    int k = s * 32 + q * 8 + j;
                    bf[j] = (short)Wlds[k * 64 + ((n + 2 * k) & 63)];
                }
            }
            #pragma unroll
            for (int mt = 0; mt < 16; ++mt) {
                int m = mt * 16 + m16;
                short8 af = *(const short8*)&Xlds[m * 64 + ((((s << 2) + q) ^ (m & 7)) << 3)];
                acc[mt] = __builtin_amdgcn_mfma_f32_16x16x32_bf16(af, bf, acc[mt], 0, 0, 0);
            }
        }
        __syncthreads();
    }
    // epilogue: fp32 partial (C/D layout: col=lane&15, row=q*4+reg within 16-tile)
    float* Pp = P + (size_t)ks * PHALF;
    const int col = n0 + w * 16 + m16;
    #pragma unroll
    for (int mt = 0; mt < 16; ++mt) {
        #pragma unroll
        for (int r = 0; r < 4; ++r) {
            int row = mt * 16 + q * 4 + r;
            Pp[(size_t)row * NBIG + col] = acc[mt][r];
        }
    }
}

// sum 4 partials -> bf16 X_next [256][8192]
__global__ __launch_bounds__(256) void reduce_mid_kernel(const float* __restrict__ P,
                                                         uint32_t* __restrict__ Xn) {
    int p = blockIdx.x * 256 + threadIdx.x;
    int e = p * 2;
    float a = P[e]     + P[e + PHALF]     + P[e + 2 * PHALF]     + P[e + 3 * PHALF];
    float b = P[e + 1] + P[e + 1 + PHALF] + P[e + 1 + 2 * PHALF] + P[e + 1 + 3 * PHALF];
    Xn[p] = f2bf(a) | (f2bf(b) << 16);
}

// sum 4 partials -> leaky -> out[n][d] fp32 (transpose via LDS tiles)
__global__ __launch_bounds__(256) void reduce_final_kernel(const float* __restrict__ P,
                                                           float* __restrict__ out) {
    __shared__ float T[32][33];
    const int n0 = blockIdx.x * 32;
    const int d0 = blockIdx.y * 32;
    const int t = threadIdx.x;
    const int a = t >> 5, b = t & 31;
    #pragma unroll
    for (int i = 0; i < 4; ++i) {
        int d = i * 8 + a;
        size_t idx = (size_t)(d0 + d) * NBIG + n0 + b;
        T[d][b] = P[idx] + P[idx + PHALF] + P[idx + 2 * PHALF] + P[idx + 3 * PHALF];
    }
    __syncthreads();
    #pragma unroll
    for (int i = 0; i < 4; ++i) {
        int n = i * 8 + a;
        float v = T[b][n];
        v = v > 0.f ? v : 0.2f * v;
        out[(size_t)(n0 + n) * 256 + d0 + b] = v;
    }
}

extern "C" void kernel_launch(void* const* d_in, const int* in_sizes, int n_in,
                              void* d_out, int out_size, void* d_ws, size_t ws_size,
                              hipStream_t stream) {
    const float* Bm   = (const float*)d_in[0];  // inp_adj [E, N]
    const float* Am   = (const float*)d_in[1];  // att_adj [N, E]
    const float* embs = (const float*)d_in[2];  // [N, D]
    float* out = (float*)d_out;

    char* w = (char*)d_ws;
    auto alloc = [&](size_t bytes) -> char* {
        char* p = w;
        w += (bytes + 255) & ~(size_t)255;
        return p;
    };
    unsigned short* XT0 = (unsigned short*)alloc((size_t)MROWS * NBIG * 2);  // 4 MB
    unsigned short* XA  = (unsigned short*)alloc((size_t)MROWS * NBIG * 2);
    unsigned short* XB  = (unsigned short*)alloc((size_t)MROWS * NBIG * 2);
    float*          P   = (float*)alloc((size_t)KS * PHALF * 4);             // 32 MB

    cvtE_kernel<<<dim3(256, 8), 256, 0, stream>>>(embs, XT0);
    // G1: X1 = XT0 * A (NN)
    gemm_kernel<0><<<dim3(128, KS), 256, 0, stream>>>(XT0, Am, P);
    reduce_mid_kernel<<<4096, 256, 0, stream>>>(P, (uint32_t*)XA);
    // G2: X2 = X1 * B (NN)
    gemm_kernel<0><<<dim3(128, KS), 256, 0, stream>>>(XA, Bm, P);
    reduce_mid_kernel<<<4096, 256, 0, stream>>>(P, (uint32_t*)XB);
    // G3: X3 = X2 * B^T (NT)
    gemm_kernel<1><<<dim3(128, KS), 256, 0, stream>>>(XB, Bm, P);
    reduce_mid_kernel<<<4096, 256, 0, stream>>>(P, (uint32_t*)XA);
    // G4: C4 = X3 * A^T (NT); out = leaky(C4^T)
    gemm_kernel<1><<<dim3(128, KS), 256, 0, stream>>>(XA, Am, P);
    reduce_final_kernel<<<dim3(256, 8), 256, 0, stream>>>(P, out);

    (void)in_sizes; (void)n_in; (void)out_size; (void)ws_size;
}